// Round 2
// baseline (381.321 us; speedup 1.0000x reference)
//
#include <hip/hip_runtime.h>
#include <math.h>

typedef __bf16 bf16x8 __attribute__((ext_vector_type(8)));
typedef __bf16 bf16x4 __attribute__((ext_vector_type(4)));
typedef float  f32x4  __attribute__((ext_vector_type(4)));

#define QL    32
#define DL    256
#define DIM   256
#define NK    21
#define KSOFT 20
#define STR   264                 // LDS row stride in bf16 elems (256 + 8 pad)
#define L2E   1.4426950408889634f // log2(e)

// Grid (B, 2): one block per (batch, pair). 256 threads = 4 waves.
// Wave w -> C-subtile (qt = w>>1, dt = w&1) of the 32x32 doc-tile sim matrix.
__global__ __launch_bounds__(256, 3)
void knrm_main(const int* __restrict__ q1t, const int* __restrict__ d1t,
               const int* __restrict__ q2t, const int* __restrict__ d2t,
               const float* __restrict__ emb,
               const float* __restrict__ W0, const float* __restrict__ b0,
               const float* __restrict__ W1, const float* __restrict__ b1,
               const float* __restrict__ W2, const float* __restrict__ b2,
               float* __restrict__ lg, int B)
{
    const int b    = blockIdx.x;
    const int pair = blockIdx.y;
    const int tid  = threadIdx.x;
    const int wave = tid >> 6;
    const int lane = tid & 63;
    const int qt   = wave >> 1;   // 0..1 : q subtile
    const int dt   = wave & 1;    // 0..1 : d subtile
    const int g    = lane >> 4;   // 0..3
    const int cl   = lane & 15;   // 0..15

    const int* qtok = pair ? q2t : q1t;
    const int* dtok = pair ? d2t : d1t;

    __shared__ __align__(16) __bf16 qbuf[QL * STR];
    __shared__ __align__(16) __bf16 dbuf[32 * STR];
    __shared__ float qinv_s[QL];
    __shared__ float dinv_s[32];
    __shared__ float Sqk[QL * NK];
    __shared__ int   dtok_s[DL];
    __shared__ int   qtok_s[QL];
    __shared__ float km[NK];
    __shared__ float h0[10];
    __shared__ float h1[5];

    if (tid < QL) qtok_s[tid] = qtok[b * QL + tid];
    dtok_s[tid] = dtok[b * DL + tid];
    for (int e = tid; e < QL * NK; e += 256) Sqk[e] = 0.0f;
    if (tid < NK) km[tid] = 0.0f;
    __syncthreads();

    // ---- stage query rows (raw bf16; norms computed off the write path)
    {
        int   toks[8];
        #pragma unroll
        for (int i = 0; i < 8; ++i) toks[i] = qtok_s[wave * 8 + i];
        float4 v[8];
        #pragma unroll
        for (int i = 0; i < 8; ++i)
            v[i] = reinterpret_cast<const float4*>(emb + (size_t)toks[i] * DIM)[lane];
        #pragma unroll
        for (int i = 0; i < 8; ++i) {
            bf16x4 o;
            o[0] = (__bf16)v[i].x; o[1] = (__bf16)v[i].y;
            o[2] = (__bf16)v[i].z; o[3] = (__bf16)v[i].w;
            *reinterpret_cast<bf16x4*>(&qbuf[(wave*8 + i) * STR + lane * 4]) = o;
        }
        float s[8];
        #pragma unroll
        for (int i = 0; i < 8; ++i)
            s[i] = v[i].x*v[i].x + v[i].y*v[i].y + v[i].z*v[i].z + v[i].w*v[i].w;
        #pragma unroll
        for (int m = 32; m; m >>= 1) {
            #pragma unroll
            for (int i = 0; i < 8; ++i) s[i] += __shfl_xor(s[i], m);
        }
        if (lane == 0) {
            #pragma unroll
            for (int i = 0; i < 8; ++i)
                qinv_s[wave*8 + i] = rsqrtf(fmaxf(s[i], 1e-16f));
        }
    }

    int qtk[4];
    #pragma unroll
    for (int i = 0; i < 4; ++i) qtk[i] = qtok_s[qt * 16 + g * 4 + i];

    float acc[4 * NK];
    #pragma unroll
    for (int e = 0; e < 4 * NK; ++e) acc[e] = 0.0f;

    for (int tile = 0; tile < 8; ++tile) {
        // ---- stage 32 doc rows (raw bf16 + deferred norm reduce)
        {
            int   toks[8];
            #pragma unroll
            for (int i = 0; i < 8; ++i) toks[i] = dtok_s[tile * 32 + wave * 8 + i];
            float4 v[8];
            #pragma unroll
            for (int i = 0; i < 8; ++i)
                v[i] = reinterpret_cast<const float4*>(emb + (size_t)toks[i] * DIM)[lane];
            #pragma unroll
            for (int i = 0; i < 8; ++i) {
                bf16x4 o;
                o[0] = (__bf16)v[i].x; o[1] = (__bf16)v[i].y;
                o[2] = (__bf16)v[i].z; o[3] = (__bf16)v[i].w;
                *reinterpret_cast<bf16x4*>(&dbuf[(wave*8 + i) * STR + lane * 4]) = o;
            }
            float s[8];
            #pragma unroll
            for (int i = 0; i < 8; ++i)
                s[i] = v[i].x*v[i].x + v[i].y*v[i].y + v[i].z*v[i].z + v[i].w*v[i].w;
            #pragma unroll
            for (int m = 32; m; m >>= 1) {
                #pragma unroll
                for (int i = 0; i < 8; ++i) s[i] += __shfl_xor(s[i], m);
            }
            if (lane == 0) {
                #pragma unroll
                for (int i = 0; i < 8; ++i)
                    dinv_s[wave*8 + i] = rsqrtf(fmaxf(s[i], 1e-16f));
            }
        }
        __syncthreads();

        // ---- 16x16 MFMA over K=256 on raw bf16
        f32x4 cf = {0.0f, 0.0f, 0.0f, 0.0f};
        #pragma unroll
        for (int ks = 0; ks < 8; ++ks) {
            bf16x8 af  = *reinterpret_cast<const bf16x8*>(&qbuf[(qt*16 + cl)*STR + ks*32 + g*8]);
            bf16x8 bfr = *reinterpret_cast<const bf16x8*>(&dbuf[(dt*16 + cl)*STR + ks*32 + g*8]);
            cf = __builtin_amdgcn_mfma_f32_16x16x32_bf16(af, bfr, cf, 0, 0, 0);
        }

        // ---- Gaussian kernels off the C fragment; normalize via scale fixup
        float dn  = dinv_s[dt*16 + cl];
        int   dtk = dtok_s[tile*32 + dt*16 + cl];
        #pragma unroll
        for (int i = 0; i < 4; ++i) {
            float qn  = qinv_s[qt*16 + g*4 + i];
            float mm  = cf[i] * qn * dn;
            float mm2 = mm * mm;
            #pragma unroll
            for (int k = 0; k < KSOFT; ++k) {
                float mu = -0.95f + 0.1f * (float)k;          // compile-time
                float a1 = 100.0f * L2E * mu;
                float a0 = -50.0f * L2E * mu * mu;
                float arg = fmaf(a1, mm, fmaf(-50.0f * L2E, mm2, a0));
                acc[i*NK + k] += exp2f(arg);
            }
            // exact kernel (sigma=0.001) == 1[token match]
            acc[i*NK + KSOFT] += (dtk == qtk[i]) ? 1.0f : 0.0f;
        }
        __syncthreads();   // protect dbuf/dinv_s for next tile
    }

    // ---- flush per-lane partials into Sqk
    #pragma unroll
    for (int i = 0; i < 4; ++i) {
        int row = qt*16 + g*4 + i;
        #pragma unroll
        for (int k = 0; k < NK; ++k)
            atomicAdd(&Sqk[row*NK + k], acc[i*NK + k]);
    }
    __syncthreads();

    // ---- km[k] = sum_q log1p(Sqk[q][k])
    for (int e = tid; e < QL * NK; e += 256)
        atomicAdd(&km[e % NK], log1pf(Sqk[e]));
    __syncthreads();

    // ---- tiny MLP 21 -> 10 -> 5 -> 1
    if (tid < 10) {
        float h = b0[tid];
        #pragma unroll
        for (int k = 0; k < NK; ++k) h = fmaf(km[k], W0[tid*NK + k], h);
        h0[tid] = fmaxf(h, 0.0f);
    }
    __syncthreads();
    if (tid < 5) {
        float h = b1[tid];
        #pragma unroll
        for (int j = 0; j < 10; ++j) h = fmaf(h0[j], W1[tid*10 + j], h);
        h1[tid] = fmaxf(h, 0.0f);
    }
    __syncthreads();
    if (tid == 0) {
        float l = b2[0];
        #pragma unroll
        for (int j = 0; j < 5; ++j) l = fmaf(h1[j], W2[j], l);
        lg[pair * B + b] = l;
    }
}

__global__ void knrm_final(const float* __restrict__ lg, float* __restrict__ out, int B)
{
    int i = blockIdx.x * 256 + threadIdx.x;
    if (i < B) {
        float z = lg[i] - lg[B + i];
        out[i] = 1.0f / (1.0f + expf(-z));
    }
}

extern "C" void kernel_launch(void* const* d_in, const int* in_sizes, int n_in,
                              void* d_out, int out_size, void* d_ws, size_t ws_size,
                              hipStream_t stream) {
    const int*   q1  = (const int*)d_in[0];
    const int*   d1  = (const int*)d_in[1];
    const int*   q2  = (const int*)d_in[2];
    const int*   d2  = (const int*)d_in[3];
    const float* emb = (const float*)d_in[4];
    const float* W0  = (const float*)d_in[5];
    const float* b0  = (const float*)d_in[6];
    const float* W1  = (const float*)d_in[7];
    const float* b1  = (const float*)d_in[8];
    const float* W2  = (const float*)d_in[9];
    const float* b2  = (const float*)d_in[10];
    float* out = (float*)d_out;
    float* lg  = (float*)d_ws;            // 2*B floats of scratch

    const int B = in_sizes[0] / QL;       // 512
    dim3 grid(B, 2);
    knrm_main<<<grid, 256, 0, stream>>>(q1, d1, q2, d2, emb,
                                        W0, b0, W1, b1, W2, b2, lg, B);
    knrm_final<<<(B + 255) / 256, 256, 0, stream>>>(lg, out, B);
}

// Round 3
// 371.967 us; speedup vs baseline: 1.0251x; 1.0251x over previous
//
#include <hip/hip_runtime.h>
#include <math.h>

typedef __bf16 bf16x8 __attribute__((ext_vector_type(8)));
typedef __bf16 bf16x4 __attribute__((ext_vector_type(4)));
typedef float  f32x4  __attribute__((ext_vector_type(4)));

#define QL    32
#define DL    256
#define DIM   256
#define NK    21
#define KSOFT 20
#define STR   266                 // LDS row stride in bf16 (256+10: odd dword mult)
#define L2E   1.4426950408889634f // log2(e)

// ---------- Phase 1: stream-normalize the emb table into a bf16 copy in ws ----
// One wave per row: 64 lanes x float4 = the whole 1 KiB row in one load.
__global__ __launch_bounds__(256)
void knrm_prep(const float* __restrict__ emb, __bf16* __restrict__ tab, int V)
{
    const int wave = threadIdx.x >> 6;
    const int lane = threadIdx.x & 63;
    const int row  = blockIdx.x * 4 + wave;
    if (row >= V) return;

    float4 v = reinterpret_cast<const float4*>(emb + (size_t)row * DIM)[lane];
    float s = v.x*v.x + v.y*v.y + v.z*v.z + v.w*v.w;
    #pragma unroll
    for (int m = 32; m; m >>= 1) s += __shfl_xor(s, m);
    float inv = rsqrtf(fmaxf(s, 1e-16f));   // ||row|| ~16, ref eps never binds
    bf16x4 o;
    o[0] = (__bf16)(v.x * inv);
    o[1] = (__bf16)(v.y * inv);
    o[2] = (__bf16)(v.z * inv);
    o[3] = (__bf16)(v.w * inv);
    *reinterpret_cast<bf16x4*>(tab + (size_t)row * DIM + lane * 4) = o;
}

// ---------- Phase 2: per-(batch,pair) block; gather bf16 rows, MFMA, kernels --
__global__ __launch_bounds__(256, 4)
void knrm_main2(const int* __restrict__ q1t, const int* __restrict__ d1t,
                const int* __restrict__ q2t, const int* __restrict__ d2t,
                const __bf16* __restrict__ tab,
                const float* __restrict__ W0, const float* __restrict__ b0,
                const float* __restrict__ W1, const float* __restrict__ b1,
                const float* __restrict__ W2, const float* __restrict__ b2,
                float* __restrict__ lg, int B)
{
    const int b    = blockIdx.x;
    const int pair = blockIdx.y;
    const int tid  = threadIdx.x;
    const int wave = tid >> 6;
    const int lane = tid & 63;
    const int qt   = wave >> 1;
    const int dt   = wave & 1;
    const int g    = lane >> 4;
    const int cl   = lane & 15;
    const int hl   = lane & 31;     // half-wave lane
    const int hw   = lane >> 5;     // which half-wave

    const int* qtok = pair ? q2t : q1t;
    const int* dtok = pair ? d2t : d1t;

    __shared__ __align__(16) __bf16 qbuf[QL * STR];
    __shared__ __align__(16) __bf16 dbuf[32 * STR];
    __shared__ float Sqk[QL * NK];
    __shared__ int   dtok_s[DL];
    __shared__ int   qtok_s[QL];
    __shared__ float km[NK];
    __shared__ float h0[10];
    __shared__ float h1[5];

    if (tid < QL) qtok_s[tid] = qtok[b * QL + tid];
    dtok_s[tid] = dtok[b * DL + tid];
    for (int e = tid; e < QL * NK; e += 256) Sqk[e] = 0.0f;
    if (tid < NK) km[tid] = 0.0f;
    __syncthreads();

    // ---- stage 8 query rows per wave (rows pre-normalized bf16; 512 B each;
    //      one bf16x8 load covers half a row, so 2 rows per wave-load)
    {
        bf16x8 v[4];
        #pragma unroll
        for (int i = 0; i < 4; ++i) {
            int r = wave * 8 + i * 2 + hw;
            v[i] = *reinterpret_cast<const bf16x8*>(
                tab + (size_t)qtok_s[r] * DIM + hl * 8);
        }
        #pragma unroll
        for (int i = 0; i < 4; ++i) {
            int r = wave * 8 + i * 2 + hw;
            *reinterpret_cast<bf16x8*>(&qbuf[r * STR + hl * 8]) = v[i];
        }
    }

    int qtk[4];
    #pragma unroll
    for (int i = 0; i < 4; ++i) qtk[i] = qtok_s[qt * 16 + g * 4 + i];

    float acc[4 * NK];
    #pragma unroll
    for (int e = 0; e < 4 * NK; ++e) acc[e] = 0.0f;

    for (int tile = 0; tile < 8; ++tile) {
        // ---- stage 32 doc rows (8 per wave, 2 rows per load)
        {
            bf16x8 v[4];
            #pragma unroll
            for (int i = 0; i < 4; ++i) {
                int r = wave * 8 + i * 2 + hw;
                v[i] = *reinterpret_cast<const bf16x8*>(
                    tab + (size_t)dtok_s[tile * 32 + r] * DIM + hl * 8);
            }
            #pragma unroll
            for (int i = 0; i < 4; ++i) {
                int r = wave * 8 + i * 2 + hw;
                *reinterpret_cast<bf16x8*>(&dbuf[r * STR + hl * 8]) = v[i];
            }
        }
        __syncthreads();

        // ---- 16x16x32 MFMA over K=256
        f32x4 cf = {0.0f, 0.0f, 0.0f, 0.0f};
        #pragma unroll
        for (int ks = 0; ks < 8; ++ks) {
            bf16x8 af  = *reinterpret_cast<const bf16x8*>(&qbuf[(qt*16 + cl)*STR + ks*32 + g*8]);
            bf16x8 bfr = *reinterpret_cast<const bf16x8*>(&dbuf[(dt*16 + cl)*STR + ks*32 + g*8]);
            cf = __builtin_amdgcn_mfma_f32_16x16x32_bf16(af, bfr, cf, 0, 0, 0);
        }

        // ---- Gaussian kernels straight off the C fragment
        int dtk = dtok_s[tile*32 + dt*16 + cl];
        #pragma unroll
        for (int i = 0; i < 4; ++i) {
            float mm  = cf[i];
            float mm2 = mm * mm;
            #pragma unroll
            for (int k = 0; k < KSOFT; ++k) {
                float mu = -0.95f + 0.1f * (float)k;          // compile-time
                float a1 = 100.0f * L2E * mu;
                float a0 = -50.0f * L2E * mu * mu;
                float arg = fmaf(a1, mm, fmaf(-50.0f * L2E, mm2, a0));
                acc[i*NK + k] += exp2f(arg);
            }
            // exact kernel (sigma=0.001) == 1[token match]
            acc[i*NK + KSOFT] += (dtk == qtk[i]) ? 1.0f : 0.0f;
        }
        __syncthreads();   // protect dbuf for next tile
    }

    // ---- flush per-lane partials into Sqk
    #pragma unroll
    for (int i = 0; i < 4; ++i) {
        int row = qt*16 + g*4 + i;
        #pragma unroll
        for (int k = 0; k < NK; ++k)
            atomicAdd(&Sqk[row*NK + k], acc[i*NK + k]);
    }
    __syncthreads();

    // ---- km[k] = sum_q log1p(Sqk[q][k])
    for (int e = tid; e < QL * NK; e += 256)
        atomicAdd(&km[e % NK], log1pf(Sqk[e]));
    __syncthreads();

    // ---- tiny MLP 21 -> 10 -> 5 -> 1
    if (tid < 10) {
        float h = b0[tid];
        #pragma unroll
        for (int k = 0; k < NK; ++k) h = fmaf(km[k], W0[tid*NK + k], h);
        h0[tid] = fmaxf(h, 0.0f);
    }
    __syncthreads();
    if (tid < 5) {
        float h = b1[tid];
        #pragma unroll
        for (int j = 0; j < 10; ++j) h = fmaf(h0[j], W1[tid*10 + j], h);
        h1[tid] = fmaxf(h, 0.0f);
    }
    __syncthreads();
    if (tid == 0) {
        float l = b2[0];
        #pragma unroll
        for (int j = 0; j < 5; ++j) l = fmaf(h1[j], W2[j], l);
        lg[pair * B + b] = l;
    }
}

__global__ void knrm_final(const float* __restrict__ lg, float* __restrict__ out, int B)
{
    int i = blockIdx.x * 256 + threadIdx.x;
    if (i < B) {
        float z = lg[i] - lg[B + i];
        out[i] = 1.0f / (1.0f + expf(-z));
    }
}

// ---------- Fallback (R1 kernel): used only if ws_size can't hold the table ---
__global__ __launch_bounds__(256, 2)
void knrm_mono(const int* __restrict__ q1t, const int* __restrict__ d1t,
               const int* __restrict__ q2t, const int* __restrict__ d2t,
               const float* __restrict__ emb,
               const float* __restrict__ W0, const float* __restrict__ b0,
               const float* __restrict__ W1, const float* __restrict__ b1,
               const float* __restrict__ W2, const float* __restrict__ b2,
               float* __restrict__ out)
{
    const int b    = blockIdx.x;
    const int tid  = threadIdx.x;
    const int wave = tid >> 6;
    const int lane = tid & 63;
    const int qt   = wave >> 1;
    const int dt   = wave & 1;
    const int g    = lane >> 4;
    const int cl   = lane & 15;

    __shared__ __align__(16) __bf16 qbuf[QL * STR];
    __shared__ __align__(16) __bf16 dbuf[32 * STR];
    __shared__ float Sqk[QL * NK];
    __shared__ int   dtok_s[DL];
    __shared__ int   qtok_s[QL];
    __shared__ float km[NK];
    __shared__ float h0[10];
    __shared__ float h1[5];
    __shared__ float logit[2];

    for (int pair = 0; pair < 2; ++pair) {
        const int* qtok = pair ? q2t : q1t;
        const int* dtok = pair ? d2t : d1t;

        if (tid < QL) qtok_s[tid] = qtok[b * QL + tid];
        dtok_s[tid] = dtok[b * DL + tid];
        for (int e = tid; e < QL * NK; e += 256) Sqk[e] = 0.0f;
        if (tid < NK) km[tid] = 0.0f;
        __syncthreads();

        #pragma unroll
        for (int i = 0; i < 8; ++i) {
            int row = wave * 8 + i;
            int tok = qtok_s[row];
            float4 v = reinterpret_cast<const float4*>(emb + (size_t)tok * DIM)[lane];
            float s = v.x*v.x + v.y*v.y + v.z*v.z + v.w*v.w;
            #pragma unroll
            for (int m = 32; m; m >>= 1) s += __shfl_xor(s, m);
            float inv = rsqrtf(fmaxf(s, 1e-16f));
            bf16x4 o;
            o[0] = (__bf16)(v.x * inv); o[1] = (__bf16)(v.y * inv);
            o[2] = (__bf16)(v.z * inv); o[3] = (__bf16)(v.w * inv);
            *reinterpret_cast<bf16x4*>(&qbuf[row * STR + lane * 4]) = o;
        }

        int qtk[4];
        #pragma unroll
        for (int i = 0; i < 4; ++i) qtk[i] = qtok_s[qt * 16 + g * 4 + i];

        float acc[4 * NK];
        #pragma unroll
        for (int e = 0; e < 4 * NK; ++e) acc[e] = 0.0f;

        for (int tile = 0; tile < 8; ++tile) {
            #pragma unroll
            for (int i = 0; i < 8; ++i) {
                int r = wave * 8 + i;
                int tok = dtok_s[tile * 32 + r];
                float4 v = reinterpret_cast<const float4*>(emb + (size_t)tok * DIM)[lane];
                float s = v.x*v.x + v.y*v.y + v.z*v.z + v.w*v.w;
                #pragma unroll
                for (int m = 32; m; m >>= 1) s += __shfl_xor(s, m);
                float inv = rsqrtf(fmaxf(s, 1e-16f));
                bf16x4 o;
                o[0] = (__bf16)(v.x * inv); o[1] = (__bf16)(v.y * inv);
                o[2] = (__bf16)(v.z * inv); o[3] = (__bf16)(v.w * inv);
                *reinterpret_cast<bf16x4*>(&dbuf[r * STR + lane * 4]) = o;
            }
            __syncthreads();

            f32x4 cf = {0.0f, 0.0f, 0.0f, 0.0f};
            #pragma unroll
            for (int ks = 0; ks < 8; ++ks) {
                bf16x8 af  = *reinterpret_cast<const bf16x8*>(&qbuf[(qt*16 + cl)*STR + ks*32 + g*8]);
                bf16x8 bfr = *reinterpret_cast<const bf16x8*>(&dbuf[(dt*16 + cl)*STR + ks*32 + g*8]);
                cf = __builtin_amdgcn_mfma_f32_16x16x32_bf16(af, bfr, cf, 0, 0, 0);
            }

            int dtk = dtok_s[tile*32 + dt*16 + cl];
            #pragma unroll
            for (int i = 0; i < 4; ++i) {
                float mm  = cf[i];
                float mm2 = mm * mm;
                #pragma unroll
                for (int k = 0; k < KSOFT; ++k) {
                    float mu = -0.95f + 0.1f * (float)k;
                    float a1 = 100.0f * L2E * mu;
                    float a0 = -50.0f * L2E * mu * mu;
                    float arg = fmaf(a1, mm, fmaf(-50.0f * L2E, mm2, a0));
                    acc[i*NK + k] += exp2f(arg);
                }
                acc[i*NK + KSOFT] += (dtk == qtk[i]) ? 1.0f : 0.0f;
            }
            __syncthreads();
        }

        #pragma unroll
        for (int i = 0; i < 4; ++i) {
            int row = qt*16 + g*4 + i;
            #pragma unroll
            for (int k = 0; k < NK; ++k)
                atomicAdd(&Sqk[row*NK + k], acc[i*NK + k]);
        }
        __syncthreads();

        for (int e = tid; e < QL * NK; e += 256)
            atomicAdd(&km[e % NK], log1pf(Sqk[e]));
        __syncthreads();

        if (tid < 10) {
            float h = b0[tid];
            #pragma unroll
            for (int k = 0; k < NK; ++k) h = fmaf(km[k], W0[tid*NK + k], h);
            h0[tid] = fmaxf(h, 0.0f);
        }
        __syncthreads();
        if (tid < 5) {
            float h = b1[tid];
            #pragma unroll
            for (int j = 0; j < 10; ++j) h = fmaf(h0[j], W1[tid*10 + j], h);
            h1[tid] = fmaxf(h, 0.0f);
        }
        __syncthreads();
        if (tid == 0) {
            float l = b2[0];
            #pragma unroll
            for (int j = 0; j < 5; ++j) l = fmaf(h1[j], W2[j], l);
            logit[pair] = l;
        }
        __syncthreads();
    }

    if (tid == 0) {
        float z = logit[0] - logit[1];
        out[b] = 1.0f / (1.0f + expf(-z));
    }
}

extern "C" void kernel_launch(void* const* d_in, const int* in_sizes, int n_in,
                              void* d_out, int out_size, void* d_ws, size_t ws_size,
                              hipStream_t stream) {
    const int*   q1  = (const int*)d_in[0];
    const int*   d1  = (const int*)d_in[1];
    const int*   q2  = (const int*)d_in[2];
    const int*   d2  = (const int*)d_in[3];
    const float* emb = (const float*)d_in[4];
    const float* W0  = (const float*)d_in[5];
    const float* b0  = (const float*)d_in[6];
    const float* W1  = (const float*)d_in[7];
    const float* b1  = (const float*)d_in[8];
    const float* W2  = (const float*)d_in[9];
    const float* b2  = (const float*)d_in[10];
    float* out = (float*)d_out;

    const int B = in_sizes[0] / QL;       // 512
    const int V = in_sizes[4] / DIM;      // 100000

    size_t tab_bytes = (size_t)V * DIM * sizeof(__bf16);
    size_t need = tab_bytes + 256 + (size_t)2 * B * sizeof(float);

    if (ws_size >= need) {
        __bf16* tab = (__bf16*)d_ws;
        float*  lg  = (float*)((char*)d_ws + ((tab_bytes + 255) & ~(size_t)255));

        knrm_prep<<<(V + 3) / 4, 256, 0, stream>>>(emb, tab, V);
        dim3 grid(B, 2);
        knrm_main2<<<grid, 256, 0, stream>>>(q1, d1, q2, d2, tab,
                                             W0, b0, W1, b1, W2, b2, lg, B);
        knrm_final<<<(B + 255) / 256, 256, 0, stream>>>(lg, out, B);
    } else {
        knrm_mono<<<B, 256, 0, stream>>>(q1, d1, q2, d2, emb,
                                         W0, b0, W1, b1, W2, b2, out);
    }
}

// Round 4
// 367.933 us; speedup vs baseline: 1.0364x; 1.0110x over previous
//
#include <hip/hip_runtime.h>
#include <math.h>

typedef __bf16 bf16x8 __attribute__((ext_vector_type(8)));
typedef __bf16 bf16x4 __attribute__((ext_vector_type(4)));
typedef float  f32x4  __attribute__((ext_vector_type(4)));

#define QL    32
#define DL    256
#define DIM   256
#define NK    21
#define KSOFT 20
#define STR   264                 // LDS row stride in bf16: 528 B, 16-B aligned, +8 pad
#define L2E   1.4426950408889634f // log2(e)

#if __has_builtin(__builtin_amdgcn_exp2f)
#define EXP2F(x) __builtin_amdgcn_exp2f(x)
#else
#define EXP2F(x) exp2f(x)
#endif

// ---------- Phase 1: stream-normalize the emb table into a bf16 copy in ws ----
__global__ __launch_bounds__(256)
void knrm_prep(const float* __restrict__ emb, __bf16* __restrict__ tab, int V)
{
    const int wave = threadIdx.x >> 6;
    const int lane = threadIdx.x & 63;
    const int row  = blockIdx.x * 4 + wave;
    if (row >= V) return;

    float4 v = reinterpret_cast<const float4*>(emb + (size_t)row * DIM)[lane];
    float s = v.x*v.x + v.y*v.y + v.z*v.z + v.w*v.w;
    #pragma unroll
    for (int m = 32; m; m >>= 1) s += __shfl_xor(s, m);
    float inv = rsqrtf(fmaxf(s, 1e-16f));   // ||row|| ~16, ref eps never binds
    bf16x4 o;
    o[0] = (__bf16)(v.x * inv);
    o[1] = (__bf16)(v.y * inv);
    o[2] = (__bf16)(v.z * inv);
    o[3] = (__bf16)(v.w * inv);
    *reinterpret_cast<bf16x4*>(tab + (size_t)row * DIM + lane * 4) = o;
}

// ---------- Phase 2: per-(batch,pair) block; reg-prefetch pipelined gather ----
__global__ __launch_bounds__(256, 4)
void knrm_main2(const int* __restrict__ q1t, const int* __restrict__ d1t,
                const int* __restrict__ q2t, const int* __restrict__ d2t,
                const __bf16* __restrict__ tab,
                const float* __restrict__ W0, const float* __restrict__ b0,
                const float* __restrict__ W1, const float* __restrict__ b1,
                const float* __restrict__ W2, const float* __restrict__ b2,
                float* __restrict__ lg, int B)
{
    const int b    = blockIdx.x;
    const int pair = blockIdx.y;
    const int tid  = threadIdx.x;
    const int wave = tid >> 6;
    const int lane = tid & 63;
    const int qt   = wave >> 1;
    const int dt   = wave & 1;
    const int g    = lane >> 4;
    const int cl   = lane & 15;
    const int hl   = lane & 31;     // half-wave lane
    const int hw   = lane >> 5;     // which half-wave

    const int* qtok = pair ? q2t : q1t;
    const int* dtok = pair ? d2t : d1t;

    __shared__ __align__(16) __bf16 qbuf[QL * STR];
    __shared__ __align__(16) __bf16 dbuf[32 * STR];
    __shared__ float Sqk[QL * NK];
    __shared__ int   dtok_s[DL];
    __shared__ int   qtok_s[QL];
    __shared__ float km[NK];
    __shared__ float h0[10];
    __shared__ float h1[5];

    if (tid < QL) qtok_s[tid] = qtok[b * QL + tid];
    dtok_s[tid] = dtok[b * DL + tid];
    for (int e = tid; e < QL * NK; e += 256) Sqk[e] = 0.0f;
    if (tid < NK) km[tid] = 0.0f;
    __syncthreads();

    // ---- stage 8 query rows per wave (pre-normalized bf16; 2 rows per load)
    {
        bf16x8 qv[4];
        #pragma unroll
        for (int i = 0; i < 4; ++i) {
            int r = wave * 8 + i * 2 + hw;
            qv[i] = *reinterpret_cast<const bf16x8*>(
                tab + (size_t)qtok_s[r] * DIM + hl * 8);
        }
        #pragma unroll
        for (int i = 0; i < 4; ++i) {
            int r = wave * 8 + i * 2 + hw;
            *reinterpret_cast<bf16x8*>(&qbuf[r * STR + hl * 8]) = qv[i];
        }
    }

    // ---- prefetch doc tile 0 into registers
    bf16x8 dreg[4];
    #pragma unroll
    for (int i = 0; i < 4; ++i) {
        int r = wave * 8 + i * 2 + hw;
        dreg[i] = *reinterpret_cast<const bf16x8*>(
            tab + (size_t)dtok_s[r] * DIM + hl * 8);
    }

    int qtk[4];
    #pragma unroll
    for (int i = 0; i < 4; ++i) qtk[i] = qtok_s[qt * 16 + g * 4 + i];

    float acc[4 * NK];
    #pragma unroll
    for (int e = 0; e < 4 * NK; ++e) acc[e] = 0.0f;

    for (int tile = 0; tile < 8; ++tile) {
        __syncthreads();   // dbuf free (prev tile's readers done); qbuf ready @t=0

        // ---- commit prefetched rows to LDS
        #pragma unroll
        for (int i = 0; i < 4; ++i) {
            int r = wave * 8 + i * 2 + hw;
            *reinterpret_cast<bf16x8*>(&dbuf[r * STR + hl * 8]) = dreg[i];
        }
        // ---- issue next tile's gathers; they fly during this tile's compute
        if (tile < 7) {
            #pragma unroll
            for (int i = 0; i < 4; ++i) {
                int r = wave * 8 + i * 2 + hw;
                dreg[i] = *reinterpret_cast<const bf16x8*>(
                    tab + (size_t)dtok_s[(tile + 1) * 32 + r] * DIM + hl * 8);
            }
        }
        __syncthreads();   // dbuf (tile) visible to all waves

        // ---- 16x16x32 MFMA over K=256
        f32x4 cf = {0.0f, 0.0f, 0.0f, 0.0f};
        #pragma unroll
        for (int ks = 0; ks < 8; ++ks) {
            bf16x8 af  = *reinterpret_cast<const bf16x8*>(&qbuf[(qt*16 + cl)*STR + ks*32 + g*8]);
            bf16x8 bfr = *reinterpret_cast<const bf16x8*>(&dbuf[(dt*16 + cl)*STR + ks*32 + g*8]);
            cf = __builtin_amdgcn_mfma_f32_16x16x32_bf16(af, bfr, cf, 0, 0, 0);
        }

        // ---- Gaussian kernels straight off the C fragment
        int dtk = dtok_s[tile*32 + dt*16 + cl];
        #pragma unroll
        for (int i = 0; i < 4; ++i) {
            float mm  = cf[i];
            float mm2 = mm * mm;
            #pragma unroll
            for (int k = 0; k < KSOFT; ++k) {
                float mu = -0.95f + 0.1f * (float)k;          // compile-time
                float a1 = 100.0f * L2E * mu;
                float a0 = -50.0f * L2E * mu * mu;
                float arg = fmaf(a1, mm, fmaf(-50.0f * L2E, mm2, a0));
                acc[i*NK + k] += EXP2F(arg);
            }
            // exact kernel (sigma=0.001) == 1[token match]
            acc[i*NK + KSOFT] += (dtk == qtk[i]) ? 1.0f : 0.0f;
        }
    }

    // ---- flush per-lane partials into Sqk
    #pragma unroll
    for (int i = 0; i < 4; ++i) {
        int row = qt*16 + g*4 + i;
        #pragma unroll
        for (int k = 0; k < NK; ++k)
            atomicAdd(&Sqk[row*NK + k], acc[i*NK + k]);
    }
    __syncthreads();

    // ---- km[k] = sum_q log1p(Sqk[q][k])
    for (int e = tid; e < QL * NK; e += 256)
        atomicAdd(&km[e % NK], log1pf(Sqk[e]));
    __syncthreads();

    // ---- tiny MLP 21 -> 10 -> 5 -> 1
    if (tid < 10) {
        float h = b0[tid];
        #pragma unroll
        for (int k = 0; k < NK; ++k) h = fmaf(km[k], W0[tid*NK + k], h);
        h0[tid] = fmaxf(h, 0.0f);
    }
    __syncthreads();
    if (tid < 5) {
        float h = b1[tid];
        #pragma unroll
        for (int j = 0; j < 10; ++j) h = fmaf(h0[j], W1[tid*10 + j], h);
        h1[tid] = fmaxf(h, 0.0f);
    }
    __syncthreads();
    if (tid == 0) {
        float l = b2[0];
        #pragma unroll
        for (int j = 0; j < 5; ++j) l = fmaf(h1[j], W2[j], l);
        lg[pair * B + b] = l;
    }
}

__global__ void knrm_final(const float* __restrict__ lg, float* __restrict__ out, int B)
{
    int i = blockIdx.x * 256 + threadIdx.x;
    if (i < B) {
        float z = lg[i] - lg[B + i];
        out[i] = 1.0f / (1.0f + expf(-z));
    }
}

// ---------- Fallback (monolithic): only if ws can't hold the bf16 table ------
__global__ __launch_bounds__(256, 2)
void knrm_mono(const int* __restrict__ q1t, const int* __restrict__ d1t,
               const int* __restrict__ q2t, const int* __restrict__ d2t,
               const float* __restrict__ emb,
               const float* __restrict__ W0, const float* __restrict__ b0,
               const float* __restrict__ W1, const float* __restrict__ b1,
               const float* __restrict__ W2, const float* __restrict__ b2,
               float* __restrict__ out)
{
    const int b    = blockIdx.x;
    const int tid  = threadIdx.x;
    const int wave = tid >> 6;
    const int lane = tid & 63;
    const int qt   = wave >> 1;
    const int dt   = wave & 1;
    const int g    = lane >> 4;
    const int cl   = lane & 15;

    __shared__ __align__(16) __bf16 qbuf[QL * STR];
    __shared__ __align__(16) __bf16 dbuf[32 * STR];
    __shared__ float Sqk[QL * NK];
    __shared__ int   dtok_s[DL];
    __shared__ int   qtok_s[QL];
    __shared__ float km[NK];
    __shared__ float h0[10];
    __shared__ float h1[5];
    __shared__ float logit[2];

    for (int pair = 0; pair < 2; ++pair) {
        const int* qtok = pair ? q2t : q1t;
        const int* dtok = pair ? d2t : d1t;

        if (tid < QL) qtok_s[tid] = qtok[b * QL + tid];
        dtok_s[tid] = dtok[b * DL + tid];
        for (int e = tid; e < QL * NK; e += 256) Sqk[e] = 0.0f;
        if (tid < NK) km[tid] = 0.0f;
        __syncthreads();

        #pragma unroll
        for (int i = 0; i < 8; ++i) {
            int row = wave * 8 + i;
            int tok = qtok_s[row];
            float4 v = reinterpret_cast<const float4*>(emb + (size_t)tok * DIM)[lane];
            float s = v.x*v.x + v.y*v.y + v.z*v.z + v.w*v.w;
            #pragma unroll
            for (int m = 32; m; m >>= 1) s += __shfl_xor(s, m);
            float inv = rsqrtf(fmaxf(s, 1e-16f));
            bf16x4 o;
            o[0] = (__bf16)(v.x * inv); o[1] = (__bf16)(v.y * inv);
            o[2] = (__bf16)(v.z * inv); o[3] = (__bf16)(v.w * inv);
            *reinterpret_cast<bf16x4*>(&qbuf[row * STR + lane * 4]) = o;
        }

        int qtk[4];
        #pragma unroll
        for (int i = 0; i < 4; ++i) qtk[i] = qtok_s[qt * 16 + g * 4 + i];

        float acc[4 * NK];
        #pragma unroll
        for (int e = 0; e < 4 * NK; ++e) acc[e] = 0.0f;

        for (int tile = 0; tile < 8; ++tile) {
            #pragma unroll
            for (int i = 0; i < 8; ++i) {
                int r = wave * 8 + i;
                int tok = dtok_s[tile * 32 + r];
                float4 v = reinterpret_cast<const float4*>(emb + (size_t)tok * DIM)[lane];
                float s = v.x*v.x + v.y*v.y + v.z*v.z + v.w*v.w;
                #pragma unroll
                for (int m = 32; m; m >>= 1) s += __shfl_xor(s, m);
                float inv = rsqrtf(fmaxf(s, 1e-16f));
                bf16x4 o;
                o[0] = (__bf16)(v.x * inv); o[1] = (__bf16)(v.y * inv);
                o[2] = (__bf16)(v.z * inv); o[3] = (__bf16)(v.w * inv);
                *reinterpret_cast<bf16x4*>(&dbuf[r * STR + lane * 4]) = o;
            }
            __syncthreads();

            f32x4 cf = {0.0f, 0.0f, 0.0f, 0.0f};
            #pragma unroll
            for (int ks = 0; ks < 8; ++ks) {
                bf16x8 af  = *reinterpret_cast<const bf16x8*>(&qbuf[(qt*16 + cl)*STR + ks*32 + g*8]);
                bf16x8 bfr = *reinterpret_cast<const bf16x8*>(&dbuf[(dt*16 + cl)*STR + ks*32 + g*8]);
                cf = __builtin_amdgcn_mfma_f32_16x16x32_bf16(af, bfr, cf, 0, 0, 0);
            }

            int dtk = dtok_s[tile*32 + dt*16 + cl];
            #pragma unroll
            for (int i = 0; i < 4; ++i) {
                float mm  = cf[i];
                float mm2 = mm * mm;
                #pragma unroll
                for (int k = 0; k < KSOFT; ++k) {
                    float mu = -0.95f + 0.1f * (float)k;
                    float a1 = 100.0f * L2E * mu;
                    float a0 = -50.0f * L2E * mu * mu;
                    float arg = fmaf(a1, mm, fmaf(-50.0f * L2E, mm2, a0));
                    acc[i*NK + k] += EXP2F(arg);
                }
                acc[i*NK + KSOFT] += (dtk == qtk[i]) ? 1.0f : 0.0f;
            }
            __syncthreads();
        }

        #pragma unroll
        for (int i = 0; i < 4; ++i) {
            int row = qt*16 + g*4 + i;
            #pragma unroll
            for (int k = 0; k < NK; ++k)
                atomicAdd(&Sqk[row*NK + k], acc[i*NK + k]);
        }
        __syncthreads();

        for (int e = tid; e < QL * NK; e += 256)
            atomicAdd(&km[e % NK], log1pf(Sqk[e]));
        __syncthreads();

        if (tid < 10) {
            float h = b0[tid];
            #pragma unroll
            for (int k = 0; k < NK; ++k) h = fmaf(km[k], W0[tid*NK + k], h);
            h0[tid] = fmaxf(h, 0.0f);
        }
        __syncthreads();
        if (tid < 5) {
            float h = b1[tid];
            #pragma unroll
            for (int j = 0; j < 10; ++j) h = fmaf(h0[j], W1[tid*10 + j], h);
            h1[tid] = fmaxf(h, 0.0f);
        }
        __syncthreads();
        if (tid == 0) {
            float l = b2[0];
            #pragma unroll
            for (int j = 0; j < 5; ++j) l = fmaf(h1[j], W2[j], l);
            logit[pair] = l;
        }
        __syncthreads();
    }

    if (tid == 0) {
        float z = logit[0] - logit[1];
        out[b] = 1.0f / (1.0f + expf(-z));
    }
}

extern "C" void kernel_launch(void* const* d_in, const int* in_sizes, int n_in,
                              void* d_out, int out_size, void* d_ws, size_t ws_size,
                              hipStream_t stream) {
    const int*   q1  = (const int*)d_in[0];
    const int*   d1  = (const int*)d_in[1];
    const int*   q2  = (const int*)d_in[2];
    const int*   d2  = (const int*)d_in[3];
    const float* emb = (const float*)d_in[4];
    const float* W0  = (const float*)d_in[5];
    const float* b0  = (const float*)d_in[6];
    const float* W1  = (const float*)d_in[7];
    const float* b1  = (const float*)d_in[8];
    const float* W2  = (const float*)d_in[9];
    const float* b2  = (const float*)d_in[10];
    float* out = (float*)d_out;

    const int B = in_sizes[0] / QL;       // 512
    const int V = in_sizes[4] / DIM;      // 100000

    size_t tab_bytes = (size_t)V * DIM * sizeof(__bf16);
    size_t need = tab_bytes + 256 + (size_t)2 * B * sizeof(float);

    if (ws_size >= need) {
        __bf16* tab = (__bf16*)d_ws;
        float*  lg  = (float*)((char*)d_ws + ((tab_bytes + 255) & ~(size_t)255));

        knrm_prep<<<(V + 3) / 4, 256, 0, stream>>>(emb, tab, V);
        dim3 grid(B, 2);
        knrm_main2<<<grid, 256, 0, stream>>>(q1, d1, q2, d2, tab,
                                             W0, b0, W1, b1, W2, b2, lg, B);
        knrm_final<<<(B + 255) / 256, 256, 0, stream>>>(lg, out, B);
    } else {
        knrm_mono<<<B, 256, 0, stream>>>(q1, d1, q2, d2, emb,
                                         W0, b0, W1, b1, W2, b2, out);
    }
}

// Round 6
// 245.274 us; speedup vs baseline: 1.5547x; 1.5001x over previous
//
#include <hip/hip_runtime.h>
#include <math.h>

typedef __bf16 bf16x8 __attribute__((ext_vector_type(8)));
typedef __bf16 bf16x4 __attribute__((ext_vector_type(4)));
typedef float  f32x4  __attribute__((ext_vector_type(4)));

#define QL    32
#define DL    256
#define DIM   256
#define NK    21
#define KSOFT 20
#define STR   264                 // LDS row stride in bf16: 528 B, 16-B aligned
#define L2E   1.4426950408889634f

#if __has_builtin(__builtin_amdgcn_exp2f)
#define EXP2F(x) __builtin_amdgcn_exp2f(x)
#else
#define EXP2F(x) exp2f(x)
#endif

// ---------- Phase 1: stream-normalize the emb table into a bf16 copy in ws ----
__global__ __launch_bounds__(256)
void knrm_prep(const float* __restrict__ emb, __bf16* __restrict__ tab, int V)
{
    const int wave = threadIdx.x >> 6;
    const int lane = threadIdx.x & 63;
    const int row  = blockIdx.x * 4 + wave;
    if (row >= V) return;

    float4 v = reinterpret_cast<const float4*>(emb + (size_t)row * DIM)[lane];
    float s = v.x*v.x + v.y*v.y + v.z*v.z + v.w*v.w;
    #pragma unroll
    for (int m = 32; m; m >>= 1) s += __shfl_xor(s, m);
    float inv = rsqrtf(fmaxf(s, 1e-16f));   // ||row|| ~16, ref eps never binds
    bf16x4 o;
    o[0] = (__bf16)(v.x * inv);
    o[1] = (__bf16)(v.y * inv);
    o[2] = (__bf16)(v.z * inv);
    o[3] = (__bf16)(v.w * inv);
    *reinterpret_cast<bf16x4*>(tab + (size_t)row * DIM + lane * 4) = o;
}

// ---------- Phase 2: LDS-staged MFMA (proven path) + Smm repartition ---------
// acc shrinks 84->21 per thread: after MFMA, C frags scatter to Smm (fp32,
// aliasing dbuf storage); each thread then owns ONE q-row x 4 d-cols.
__global__ __launch_bounds__(256, 4)
void knrm_main4(const int* __restrict__ q1t, const int* __restrict__ d1t,
                const int* __restrict__ q2t, const int* __restrict__ d2t,
                const __bf16* __restrict__ tab,
                const float* __restrict__ W0, const float* __restrict__ b0,
                const float* __restrict__ W1, const float* __restrict__ b1,
                const float* __restrict__ W2, const float* __restrict__ b2,
                float* __restrict__ lg, int B)
{
    const int b    = blockIdx.x;
    const int pair = blockIdx.y;
    const int tid  = threadIdx.x;
    const int wave = tid >> 6;
    const int lane = tid & 63;
    const int qt   = wave >> 1;
    const int dt   = wave & 1;
    const int g    = lane >> 4;
    const int cl   = lane & 15;
    const int hl   = lane & 31;     // half-wave lane
    const int hw   = lane >> 5;     // which half-wave

    const int* qtok = pair ? q2t : q1t;
    const int* dtok = pair ? d2t : d1t;

    __shared__ __align__(16) __bf16 qbuf[QL * STR];
    __shared__ __align__(16) __bf16 dbuf[32 * STR];   // reused as Smm after MFMA
    float* Smm = reinterpret_cast<float*>(dbuf);      // 32 x 33 fp32 = 4224 B
    __shared__ float Sqk[QL * NK];
    __shared__ int   dtok_s[DL];
    __shared__ int   qtok_s[QL];
    __shared__ float km[NK];
    __shared__ float h0[10];
    __shared__ float h1[5];

    if (tid < QL) qtok_s[tid] = qtok[b * QL + tid];
    dtok_s[tid] = dtok[b * DL + tid];
    for (int e = tid; e < QL * NK; e += 256) Sqk[e] = 0.0f;
    if (tid < NK) km[tid] = 0.0f;
    __syncthreads();

    // ---- stage 8 query rows per wave (pre-normalized bf16; 2 rows per load)
    {
        bf16x8 qv[4];
        #pragma unroll
        for (int i = 0; i < 4; ++i) {
            int r = wave * 8 + i * 2 + hw;
            qv[i] = *reinterpret_cast<const bf16x8*>(
                tab + (size_t)qtok_s[r] * DIM + hl * 8);
        }
        #pragma unroll
        for (int i = 0; i < 4; ++i) {
            int r = wave * 8 + i * 2 + hw;
            *reinterpret_cast<bf16x8*>(&qbuf[r * STR + hl * 8]) = qv[i];
        }
    }

    // ---- prefetch doc tile 0 into registers
    bf16x8 dreg[4];
    #pragma unroll
    for (int i = 0; i < 4; ++i) {
        int r = wave * 8 + i * 2 + hw;
        dreg[i] = *reinterpret_cast<const bf16x8*>(
            tab + (size_t)dtok_s[r] * DIM + hl * 8);
    }

    // ---- per-thread eval ownership: one q-row, 4 d-cols
    const int myq  = tid >> 3;      // 0..31
    const int myj  = tid & 7;       // 0..7 -> d-cols myj*4 .. +3
    const int qtk1 = qtok_s[myq];

    float acc[NK];
    #pragma unroll
    for (int k = 0; k < NK; ++k) acc[k] = 0.0f;

    for (int tile = 0; tile < 8; ++tile) {
        __syncthreads();   // prev Smm reads done -> dbuf free; qbuf ready @t=0

        // ---- commit prefetched rows to LDS
        #pragma unroll
        for (int i = 0; i < 4; ++i) {
            int r = wave * 8 + i * 2 + hw;
            *reinterpret_cast<bf16x8*>(&dbuf[r * STR + hl * 8]) = dreg[i];
        }
        // ---- issue next tile's gathers; they fly during this tile's compute
        if (tile < 7) {
            #pragma unroll
            for (int i = 0; i < 4; ++i) {
                int r = wave * 8 + i * 2 + hw;
                dreg[i] = *reinterpret_cast<const bf16x8*>(
                    tab + (size_t)dtok_s[(tile + 1) * 32 + r] * DIM + hl * 8);
            }
        }
        __syncthreads();   // dbuf(tile) visible

        // ---- 16x16x32 MFMA over K=256
        f32x4 cf = {0.0f, 0.0f, 0.0f, 0.0f};
        #pragma unroll
        for (int ks = 0; ks < 8; ++ks) {
            bf16x8 af  = *reinterpret_cast<const bf16x8*>(&qbuf[(qt*16 + cl)*STR + ks*32 + g*8]);
            bf16x8 bfr = *reinterpret_cast<const bf16x8*>(&dbuf[(dt*16 + cl)*STR + ks*32 + g*8]);
            cf = __builtin_amdgcn_mfma_f32_16x16x32_bf16(af, bfr, cf, 0, 0, 0);
        }
        __syncthreads();   // all MFMA ds_reads done -> dbuf reusable as Smm

        // ---- scatter C frags: C[row=qt*16+g*4+i][col=dt*16+cl]
        #pragma unroll
        for (int i = 0; i < 4; ++i)
            Smm[(qt*16 + g*4 + i) * 33 + dt*16 + cl] = cf[i];
        __syncthreads();   // Smm ready

        // ---- Gaussian kernels: thread owns (myq, d = myj*4 + c)
        #pragma unroll
        for (int c = 0; c < 4; ++c) {
            int dcol  = myj * 4 + c;
            float mm  = Smm[myq * 33 + dcol];
            float mm2 = mm * mm;
            #pragma unroll
            for (int k = 0; k < KSOFT; ++k) {
                float mu = -0.95f + 0.1f * (float)k;          // compile-time
                float a1 = 100.0f * L2E * mu;
                float a0 = -50.0f * L2E * mu * mu;
                float arg = fmaf(a1, mm, fmaf(-50.0f * L2E, mm2, a0));
                acc[k] += EXP2F(arg);
            }
            // exact kernel (sigma=0.001) == 1[token match]
            acc[KSOFT] += (dtok_s[tile*32 + dcol] == qtk1) ? 1.0f : 0.0f;
        }
    }

    // ---- flush: 8 threads per q-row merge into Sqk
    #pragma unroll
    for (int k = 0; k < NK; ++k)
        atomicAdd(&Sqk[myq * NK + k], acc[k]);
    __syncthreads();

    // ---- km[k] = sum_q log1p(Sqk[q][k])
    for (int e = tid; e < QL * NK; e += 256)
        atomicAdd(&km[e % NK], log1pf(Sqk[e]));
    __syncthreads();

    // ---- tiny MLP 21 -> 10 -> 5 -> 1
    if (tid < 10) {
        float h = b0[tid];
        #pragma unroll
        for (int k = 0; k < NK; ++k) h = fmaf(km[k], W0[tid*NK + k], h);
        h0[tid] = fmaxf(h, 0.0f);
    }
    __syncthreads();
    if (tid < 5) {
        float h = b1[tid];
        #pragma unroll
        for (int j = 0; j < 10; ++j) h = fmaf(h0[j], W1[tid*10 + j], h);
        h1[tid] = fmaxf(h, 0.0f);
    }
    __syncthreads();
    if (tid == 0) {
        float l = b2[0];
        #pragma unroll
        for (int j = 0; j < 5; ++j) l = fmaf(h1[j], W2[j], l);
        lg[pair * B + b] = l;
    }
}

__global__ void knrm_final(const float* __restrict__ lg, float* __restrict__ out, int B)
{
    int i = blockIdx.x * 256 + threadIdx.x;
    if (i < B) {
        float z = lg[i] - lg[B + i];
        out[i] = 1.0f / (1.0f + expf(-z));
    }
}

// ---------- Fallback (monolithic): only if ws can't hold the bf16 table ------
__global__ __launch_bounds__(256, 2)
void knrm_mono(const int* __restrict__ q1t, const int* __restrict__ d1t,
               const int* __restrict__ q2t, const int* __restrict__ d2t,
               const float* __restrict__ emb,
               const float* __restrict__ W0, const float* __restrict__ b0,
               const float* __restrict__ W1, const float* __restrict__ b1,
               const float* __restrict__ W2, const float* __restrict__ b2,
               float* __restrict__ out)
{
    const int b    = blockIdx.x;
    const int tid  = threadIdx.x;
    const int wave = tid >> 6;
    const int lane = tid & 63;
    const int qt   = wave >> 1;
    const int dt   = wave & 1;
    const int g    = lane >> 4;
    const int cl   = lane & 15;

    __shared__ __align__(16) __bf16 qbuf[QL * STR];
    __shared__ __align__(16) __bf16 dbuf[32 * STR];
    __shared__ float Sqk[QL * NK];
    __shared__ int   dtok_s[DL];
    __shared__ int   qtok_s[QL];
    __shared__ float km[NK];
    __shared__ float h0[10];
    __shared__ float h1[5];
    __shared__ float logit[2];

    for (int pair = 0; pair < 2; ++pair) {
        const int* qtok = pair ? q2t : q1t;
        const int* dtok = pair ? d2t : d1t;

        if (tid < QL) qtok_s[tid] = qtok[b * QL + tid];
        dtok_s[tid] = dtok[b * DL + tid];
        for (int e = tid; e < QL * NK; e += 256) Sqk[e] = 0.0f;
        if (tid < NK) km[tid] = 0.0f;
        __syncthreads();

        #pragma unroll
        for (int i = 0; i < 8; ++i) {
            int row = wave * 8 + i;
            int tok = qtok_s[row];
            float4 v = reinterpret_cast<const float4*>(emb + (size_t)tok * DIM)[lane];
            float s = v.x*v.x + v.y*v.y + v.z*v.z + v.w*v.w;
            #pragma unroll
            for (int m = 32; m; m >>= 1) s += __shfl_xor(s, m);
            float inv = rsqrtf(fmaxf(s, 1e-16f));
            bf16x4 o;
            o[0] = (__bf16)(v.x * inv); o[1] = (__bf16)(v.y * inv);
            o[2] = (__bf16)(v.z * inv); o[3] = (__bf16)(v.w * inv);
            *reinterpret_cast<bf16x4*>(&qbuf[row * STR + lane * 4]) = o;
        }

        int qtk[4];
        #pragma unroll
        for (int i = 0; i < 4; ++i) qtk[i] = qtok_s[qt * 16 + g * 4 + i];

        float acc[4 * NK];
        #pragma unroll
        for (int e = 0; e < 4 * NK; ++e) acc[e] = 0.0f;

        for (int tile = 0; tile < 8; ++tile) {
            #pragma unroll
            for (int i = 0; i < 8; ++i) {
                int r = wave * 8 + i;
                int tok = dtok_s[tile * 32 + r];
                float4 v = reinterpret_cast<const float4*>(emb + (size_t)tok * DIM)[lane];
                float s = v.x*v.x + v.y*v.y + v.z*v.z + v.w*v.w;
                #pragma unroll
                for (int m = 32; m; m >>= 1) s += __shfl_xor(s, m);
                float inv = rsqrtf(fmaxf(s, 1e-16f));
                bf16x4 o;
                o[0] = (__bf16)(v.x * inv); o[1] = (__bf16)(v.y * inv);
                o[2] = (__bf16)(v.z * inv); o[3] = (__bf16)(v.w * inv);
                *reinterpret_cast<bf16x4*>(&dbuf[r * STR + lane * 4]) = o;
            }
            __syncthreads();

            f32x4 cf = {0.0f, 0.0f, 0.0f, 0.0f};
            #pragma unroll
            for (int ks = 0; ks < 8; ++ks) {
                bf16x8 af  = *reinterpret_cast<const bf16x8*>(&qbuf[(qt*16 + cl)*STR + ks*32 + g*8]);
                bf16x8 bfr = *reinterpret_cast<const bf16x8*>(&dbuf[(dt*16 + cl)*STR + ks*32 + g*8]);
                cf = __builtin_amdgcn_mfma_f32_16x16x32_bf16(af, bfr, cf, 0, 0, 0);
            }

            int dtk = dtok_s[tile*32 + dt*16 + cl];
            #pragma unroll
            for (int i = 0; i < 4; ++i) {
                float mm  = cf[i];
                float mm2 = mm * mm;
                #pragma unroll
                for (int k = 0; k < KSOFT; ++k) {
                    float mu = -0.95f + 0.1f * (float)k;
                    float a1 = 100.0f * L2E * mu;
                    float a0 = -50.0f * L2E * mu * mu;
                    float arg = fmaf(a1, mm, fmaf(-50.0f * L2E, mm2, a0));
                    acc[i*NK + k] += EXP2F(arg);
                }
                acc[i*NK + KSOFT] += (dtk == qtk[i]) ? 1.0f : 0.0f;
            }
            __syncthreads();
        }

        #pragma unroll
        for (int i = 0; i < 4; ++i) {
            int row = qt*16 + g*4 + i;
            #pragma unroll
            for (int k = 0; k < NK; ++k)
                atomicAdd(&Sqk[row*NK + k], acc[i*NK + k]);
        }
        __syncthreads();

        for (int e = tid; e < QL * NK; e += 256)
            atomicAdd(&km[e % NK], log1pf(Sqk[e]));
        __syncthreads();

        if (tid < 10) {
            float h = b0[tid];
            #pragma unroll
            for (int k = 0; k < NK; ++k) h = fmaf(km[k], W0[tid*NK + k], h);
            h0[tid] = fmaxf(h, 0.0f);
        }
        __syncthreads();
        if (tid < 5) {
            float h = b1[tid];
            #pragma unroll
            for (int j = 0; j < 10; ++j) h = fmaf(h0[j], W1[tid*10 + j], h);
            h1[tid] = fmaxf(h, 0.0f);
        }
        __syncthreads();
        if (tid == 0) {
            float l = b2[0];
            #pragma unroll
            for (int j = 0; j < 5; ++j) l = fmaf(h1[j], W2[j], l);
            logit[pair] = l;
        }
        __syncthreads();
    }

    if (tid == 0) {
        float z = logit[0] - logit[1];
        out[b] = 1.0f / (1.0f + expf(-z));
    }
}

extern "C" void kernel_launch(void* const* d_in, const int* in_sizes, int n_in,
                              void* d_out, int out_size, void* d_ws, size_t ws_size,
                              hipStream_t stream) {
    const int*   q1  = (const int*)d_in[0];
    const int*   d1  = (const int*)d_in[1];
    const int*   q2  = (const int*)d_in[2];
    const int*   d2  = (const int*)d_in[3];
    const float* emb = (const float*)d_in[4];
    const float* W0  = (const float*)d_in[5];
    const float* b0  = (const float*)d_in[6];
    const float* W1  = (const float*)d_in[7];
    const float* b1  = (const float*)d_in[8];
    const float* W2  = (const float*)d_in[9];
    const float* b2  = (const float*)d_in[10];
    float* out = (float*)d_out;

    const int B = in_sizes[0] / QL;       // 512
    const int V = in_sizes[4] / DIM;      // 100000

    size_t tab_bytes = (size_t)V * DIM * sizeof(__bf16);
    size_t need = tab_bytes + 256 + (size_t)2 * B * sizeof(float);

    if (ws_size >= need) {
        __bf16* tab = (__bf16*)d_ws;
        float*  lg  = (float*)((char*)d_ws + ((tab_bytes + 255) & ~(size_t)255));

        knrm_prep<<<(V + 3) / 4, 256, 0, stream>>>(emb, tab, V);
        dim3 grid(B, 2);
        knrm_main4<<<grid, 256, 0, stream>>>(q1, d1, q2, d2, tab,
                                             W0, b0, W1, b1, W2, b2, lg, B);
        knrm_final<<<(B + 255) / 256, 256, 0, stream>>>(lg, out, B);
    } else {
        knrm_mono<<<B, 256, 0, stream>>>(q1, d1, q2, d2, emb,
                                         W0, b0, W1, b1, W2, b2, out);
    }
}

// Round 7
// 239.743 us; speedup vs baseline: 1.5905x; 1.0231x over previous
//
#include <hip/hip_runtime.h>
#include <math.h>

typedef __bf16 bf16x8 __attribute__((ext_vector_type(8)));
typedef __bf16 bf16x4 __attribute__((ext_vector_type(4)));
typedef float  f32x4  __attribute__((ext_vector_type(4)));

#define QL    32
#define DL    256
#define DIM   256
#define NK    21
#define KSOFT 20
#define STR   264                 // LDS row stride in bf16: 528 B, 16-B aligned
#define L2E   1.4426950408889634f

#if __has_builtin(__builtin_amdgcn_exp2f)
#define EXP2F(x) __builtin_amdgcn_exp2f(x)
#else
#define EXP2F(x) exp2f(x)
#endif

// ---------- Phase 1: stream-normalize the emb table into a bf16 copy in ws ----
// 2 rows per wave for load ILP; 8 rows per 256-thread block.
__global__ __launch_bounds__(256)
void knrm_prep(const float* __restrict__ emb, __bf16* __restrict__ tab, int V)
{
    const int wave = threadIdx.x >> 6;
    const int lane = threadIdx.x & 63;
    const int row0 = (blockIdx.x * 4 + wave) * 2;
    if (row0 >= V) return;                     // V even -> row0+1 also valid

    float4 a = reinterpret_cast<const float4*>(emb + (size_t)row0 * DIM)[lane];
    float4 c = reinterpret_cast<const float4*>(emb + (size_t)(row0 + 1) * DIM)[lane];
    float sa = a.x*a.x + a.y*a.y + a.z*a.z + a.w*a.w;
    float sc = c.x*c.x + c.y*c.y + c.z*c.z + c.w*c.w;
    #pragma unroll
    for (int m = 32; m; m >>= 1) { sa += __shfl_xor(sa, m); sc += __shfl_xor(sc, m); }
    float ia = rsqrtf(fmaxf(sa, 1e-16f));      // ||row|| ~16, ref eps never binds
    float ic = rsqrtf(fmaxf(sc, 1e-16f));
    bf16x4 oa, oc;
    oa[0] = (__bf16)(a.x * ia); oa[1] = (__bf16)(a.y * ia);
    oa[2] = (__bf16)(a.z * ia); oa[3] = (__bf16)(a.w * ia);
    oc[0] = (__bf16)(c.x * ic); oc[1] = (__bf16)(c.y * ic);
    oc[2] = (__bf16)(c.z * ic); oc[3] = (__bf16)(c.w * ic);
    *reinterpret_cast<bf16x4*>(tab + (size_t)row0 * DIM + lane * 4) = oa;
    *reinterpret_cast<bf16x4*>(tab + (size_t)(row0 + 1) * DIM + lane * 4) = oc;
}

// ---------- Phase 2: LDS-staged MFMA, A=doc / B=query so C col == q-row ------
// Lane's C column (lane&15) is a FIXED q-row -> acc[21] per lane straight off
// the fragment; no Smm round-trip, only 2 barriers per tile.
__global__ __launch_bounds__(256, 4)
void knrm_main5(const int* __restrict__ q1t, const int* __restrict__ d1t,
                const int* __restrict__ q2t, const int* __restrict__ d2t,
                const __bf16* __restrict__ tab,
                const float* __restrict__ W0, const float* __restrict__ b0,
                const float* __restrict__ W1, const float* __restrict__ b1,
                const float* __restrict__ W2, const float* __restrict__ b2,
                float* __restrict__ lg, int B)
{
    const int b    = blockIdx.x;
    const int pair = blockIdx.y;
    const int tid  = threadIdx.x;
    const int wave = tid >> 6;
    const int lane = tid & 63;
    const int qt   = wave >> 1;     // q half (B operand)
    const int dt   = wave & 1;      // doc half (A operand)
    const int g    = lane >> 4;     // k-chunk group == C row group (doc rows)
    const int cl   = lane & 15;     // A row / B row / C col
    const int hl   = lane & 31;     // half-wave lane
    const int hw   = lane >> 5;     // which half-wave

    const int* qtok = pair ? q2t : q1t;
    const int* dtok = pair ? d2t : d1t;

    __shared__ __align__(16) __bf16 qbuf[QL * STR];
    __shared__ __align__(16) __bf16 dbuf[32 * STR];
    __shared__ float Sqk[QL * NK];
    __shared__ int   dtok_s[DL];
    __shared__ int   qtok_s[QL];
    __shared__ float km[NK];
    __shared__ float h0[10];
    __shared__ float h1[5];

    if (tid < QL) qtok_s[tid] = qtok[b * QL + tid];
    dtok_s[tid] = dtok[b * DL + tid];
    for (int e = tid; e < QL * NK; e += 256) Sqk[e] = 0.0f;
    if (tid < NK) km[tid] = 0.0f;
    __syncthreads();

    // ---- stage 8 query rows per wave (pre-normalized bf16; 2 rows per load)
    {
        bf16x8 qv[4];
        #pragma unroll
        for (int i = 0; i < 4; ++i) {
            int r = wave * 8 + i * 2 + hw;
            qv[i] = *reinterpret_cast<const bf16x8*>(
                tab + (size_t)qtok_s[r] * DIM + hl * 8);
        }
        #pragma unroll
        for (int i = 0; i < 4; ++i) {
            int r = wave * 8 + i * 2 + hw;
            *reinterpret_cast<bf16x8*>(&qbuf[r * STR + hl * 8]) = qv[i];
        }
    }

    // ---- prefetch doc tile 0 into registers
    bf16x8 dreg[4];
    #pragma unroll
    for (int i = 0; i < 4; ++i) {
        int r = wave * 8 + i * 2 + hw;
        dreg[i] = *reinterpret_cast<const bf16x8*>(
            tab + (size_t)dtok_s[r] * DIM + hl * 8);
    }

    // ---- this lane's q-row (C column) is fixed for the whole kernel
    const int myq  = qt * 16 + cl;
    const int qtk1 = qtok_s[myq];

    float acc[NK];
    #pragma unroll
    for (int k = 0; k < NK; ++k) acc[k] = 0.0f;

    for (int tile = 0; tile < 8; ++tile) {
        __syncthreads();   // prev tile's dbuf reads done; qbuf ready @tile=0

        // ---- commit prefetched rows to LDS
        #pragma unroll
        for (int i = 0; i < 4; ++i) {
            int r = wave * 8 + i * 2 + hw;
            *reinterpret_cast<bf16x8*>(&dbuf[r * STR + hl * 8]) = dreg[i];
        }
        // ---- issue next tile's gathers; they fly during this tile's compute
        if (tile < 7) {
            #pragma unroll
            for (int i = 0; i < 4; ++i) {
                int r = wave * 8 + i * 2 + hw;
                dreg[i] = *reinterpret_cast<const bf16x8*>(
                    tab + (size_t)dtok_s[(tile + 1) * 32 + r] * DIM + hl * 8);
            }
        }
        __syncthreads();   // dbuf(tile) visible

        // ---- 16x16x32 MFMA over K=256, A = doc rows, B = query rows
        f32x4 cf = {0.0f, 0.0f, 0.0f, 0.0f};
        #pragma unroll
        for (int ks = 0; ks < 8; ++ks) {
            bf16x8 dfr = *reinterpret_cast<const bf16x8*>(&dbuf[(dt*16 + cl)*STR + ks*32 + g*8]);
            bf16x8 qfr = *reinterpret_cast<const bf16x8*>(&qbuf[(qt*16 + cl)*STR + ks*32 + g*8]);
            cf = __builtin_amdgcn_mfma_f32_16x16x32_bf16(dfr, qfr, cf, 0, 0, 0);
        }

        // ---- eval off the fragment: cf[i] = mm[doc=tile*32+dt*16+g*4+i][q=myq]
        #pragma unroll
        for (int i = 0; i < 4; ++i) {
            float mm  = cf[i];
            float mm2 = mm * mm;
            #pragma unroll
            for (int k = 0; k < KSOFT; ++k) {
                float mu = -0.95f + 0.1f * (float)k;          // compile-time
                float a1 = 100.0f * L2E * mu;
                float a0 = -50.0f * L2E * mu * mu;
                float arg = fmaf(a1, mm, fmaf(-50.0f * L2E, mm2, a0));
                acc[k] += EXP2F(arg);
            }
            // exact kernel (sigma=0.001) == 1[token match]
            int drow = tile*32 + dt*16 + g*4 + i;
            acc[KSOFT] += (dtok_s[drow] == qtk1) ? 1.0f : 0.0f;
        }
    }

    // ---- flush: 8 lanes (4 g-groups x 2 dt-waves) merge per q-row
    #pragma unroll
    for (int k = 0; k < NK; ++k)
        atomicAdd(&Sqk[myq * NK + k], acc[k]);
    __syncthreads();

    // ---- km[k] = sum_q log1p(Sqk[q][k])
    for (int e = tid; e < QL * NK; e += 256)
        atomicAdd(&km[e % NK], log1pf(Sqk[e]));
    __syncthreads();

    // ---- tiny MLP 21 -> 10 -> 5 -> 1
    if (tid < 10) {
        float h = b0[tid];
        #pragma unroll
        for (int k = 0; k < NK; ++k) h = fmaf(km[k], W0[tid*NK + k], h);
        h0[tid] = fmaxf(h, 0.0f);
    }
    __syncthreads();
    if (tid < 5) {
        float h = b1[tid];
        #pragma unroll
        for (int j = 0; j < 10; ++j) h = fmaf(h0[j], W1[tid*10 + j], h);
        h1[tid] = fmaxf(h, 0.0f);
    }
    __syncthreads();
    if (tid == 0) {
        float l = b2[0];
        #pragma unroll
        for (int j = 0; j < 5; ++j) l = fmaf(h1[j], W2[j], l);
        lg[pair * B + b] = l;
    }
}

__global__ void knrm_final(const float* __restrict__ lg, float* __restrict__ out, int B)
{
    int i = blockIdx.x * 256 + threadIdx.x;
    if (i < B) {
        float z = lg[i] - lg[B + i];
        out[i] = 1.0f / (1.0f + expf(-z));
    }
}

// ---------- Fallback (monolithic): only if ws can't hold the bf16 table ------
__global__ __launch_bounds__(256, 2)
void knrm_mono(const int* __restrict__ q1t, const int* __restrict__ d1t,
               const int* __restrict__ q2t, const int* __restrict__ d2t,
               const float* __restrict__ emb,
               const float* __restrict__ W0, const float* __restrict__ b0,
               const float* __restrict__ W1, const float* __restrict__ b1,
               const float* __restrict__ W2, const float* __restrict__ b2,
               float* __restrict__ out)
{
    const int b    = blockIdx.x;
    const int tid  = threadIdx.x;
    const int wave = tid >> 6;
    const int lane = tid & 63;
    const int qt   = wave >> 1;
    const int dt   = wave & 1;
    const int g    = lane >> 4;
    const int cl   = lane & 15;

    __shared__ __align__(16) __bf16 qbuf[QL * STR];
    __shared__ __align__(16) __bf16 dbuf[32 * STR];
    __shared__ float Sqk[QL * NK];
    __shared__ int   dtok_s[DL];
    __shared__ int   qtok_s[QL];
    __shared__ float km[NK];
    __shared__ float h0[10];
    __shared__ float h1[5];
    __shared__ float logit[2];

    for (int pair = 0; pair < 2; ++pair) {
        const int* qtok = pair ? q2t : q1t;
        const int* dtok = pair ? d2t : d1t;

        if (tid < QL) qtok_s[tid] = qtok[b * QL + tid];
        dtok_s[tid] = dtok[b * DL + tid];
        for (int e = tid; e < QL * NK; e += 256) Sqk[e] = 0.0f;
        if (tid < NK) km[tid] = 0.0f;
        __syncthreads();

        #pragma unroll
        for (int i = 0; i < 8; ++i) {
            int row = wave * 8 + i;
            int tok = qtok_s[row];
            float4 v = reinterpret_cast<const float4*>(emb + (size_t)tok * DIM)[lane];
            float s = v.x*v.x + v.y*v.y + v.z*v.z + v.w*v.w;
            #pragma unroll
            for (int m = 32; m; m >>= 1) s += __shfl_xor(s, m);
            float inv = rsqrtf(fmaxf(s, 1e-16f));
            bf16x4 o;
            o[0] = (__bf16)(v.x * inv); o[1] = (__bf16)(v.y * inv);
            o[2] = (__bf16)(v.z * inv); o[3] = (__bf16)(v.w * inv);
            *reinterpret_cast<bf16x4*>(&qbuf[row * STR + lane * 4]) = o;
        }

        int qtk[4];
        #pragma unroll
        for (int i = 0; i < 4; ++i) qtk[i] = qtok_s[qt * 16 + g * 4 + i];

        float acc[4 * NK];
        #pragma unroll
        for (int e = 0; e < 4 * NK; ++e) acc[e] = 0.0f;

        for (int tile = 0; tile < 8; ++tile) {
            #pragma unroll
            for (int i = 0; i < 8; ++i) {
                int r = wave * 8 + i;
                int tok = dtok_s[tile * 32 + r];
                float4 v = reinterpret_cast<const float4*>(emb + (size_t)tok * DIM)[lane];
                float s = v.x*v.x + v.y*v.y + v.z*v.z + v.w*v.w;
                #pragma unroll
                for (int m = 32; m; m >>= 1) s += __shfl_xor(s, m);
                float inv = rsqrtf(fmaxf(s, 1e-16f));
                bf16x4 o;
                o[0] = (__bf16)(v.x * inv); o[1] = (__bf16)(v.y * inv);
                o[2] = (__bf16)(v.z * inv); o[3] = (__bf16)(v.w * inv);
                *reinterpret_cast<bf16x4*>(&dbuf[r * STR + lane * 4]) = o;
            }
            __syncthreads();

            f32x4 cf = {0.0f, 0.0f, 0.0f, 0.0f};
            #pragma unroll
            for (int ks = 0; ks < 8; ++ks) {
                bf16x8 af  = *reinterpret_cast<const bf16x8*>(&qbuf[(qt*16 + cl)*STR + ks*32 + g*8]);
                bf16x8 bfr = *reinterpret_cast<const bf16x8*>(&dbuf[(dt*16 + cl)*STR + ks*32 + g*8]);
                cf = __builtin_amdgcn_mfma_f32_16x16x32_bf16(af, bfr, cf, 0, 0, 0);
            }

            int dtk = dtok_s[tile*32 + dt*16 + cl];
            #pragma unroll
            for (int i = 0; i < 4; ++i) {
                float mm  = cf[i];
                float mm2 = mm * mm;
                #pragma unroll
                for (int k = 0; k < KSOFT; ++k) {
                    float mu = -0.95f + 0.1f * (float)k;
                    float a1 = 100.0f * L2E * mu;
                    float a0 = -50.0f * L2E * mu * mu;
                    float arg = fmaf(a1, mm, fmaf(-50.0f * L2E, mm2, a0));
                    acc[i*NK + k] += EXP2F(arg);
                }
                acc[i*NK + KSOFT] += (dtk == qtk[i]) ? 1.0f : 0.0f;
            }
            __syncthreads();
        }

        #pragma unroll
        for (int i = 0; i < 4; ++i) {
            int row = qt*16 + g*4 + i;
            #pragma unroll
            for (int k = 0; k < NK; ++k)
                atomicAdd(&Sqk[row*NK + k], acc[i*NK + k]);
        }
        __syncthreads();

        for (int e = tid; e < QL * NK; e += 256)
            atomicAdd(&km[e % NK], log1pf(Sqk[e]));
        __syncthreads();

        if (tid < 10) {
            float h = b0[tid];
            #pragma unroll
            for (int k = 0; k < NK; ++k) h = fmaf(km[k], W0[tid*NK + k], h);
            h0[tid] = fmaxf(h, 0.0f);
        }
        __syncthreads();
        if (tid < 5) {
            float h = b1[tid];
            #pragma unroll
            for (int j = 0; j < 10; ++j) h = fmaf(h0[j], W1[tid*10 + j], h);
            h1[tid] = fmaxf(h, 0.0f);
        }
        __syncthreads();
        if (tid == 0) {
            float l = b2[0];
            #pragma unroll
            for (int j = 0; j < 5; ++j) l = fmaf(h1[j], W2[j], l);
            logit[pair] = l;
        }
        __syncthreads();
    }

    if (tid == 0) {
        float z = logit[0] - logit[1];
        out[b] = 1.0f / (1.0f + expf(-z));
    }
}

extern "C" void kernel_launch(void* const* d_in, const int* in_sizes, int n_in,
                              void* d_out, int out_size, void* d_ws, size_t ws_size,
                              hipStream_t stream) {
    const int*   q1  = (const int*)d_in[0];
    const int*   d1  = (const int*)d_in[1];
    const int*   q2  = (const int*)d_in[2];
    const int*   d2  = (const int*)d_in[3];
    const float* emb = (const float*)d_in[4];
    const float* W0  = (const float*)d_in[5];
    const float* b0  = (const float*)d_in[6];
    const float* W1  = (const float*)d_in[7];
    const float* b1  = (const float*)d_in[8];
    const float* W2  = (const float*)d_in[9];
    const float* b2  = (const float*)d_in[10];
    float* out = (float*)d_out;

    const int B = in_sizes[0] / QL;       // 512
    const int V = in_sizes[4] / DIM;      // 100000

    size_t tab_bytes = (size_t)V * DIM * sizeof(__bf16);
    size_t need = tab_bytes + 256 + (size_t)2 * B * sizeof(float);

    if (ws_size >= need) {
        __bf16* tab = (__bf16*)d_ws;
        float*  lg  = (float*)((char*)d_ws + ((tab_bytes + 255) & ~(size_t)255));

        knrm_prep<<<(V/2 + 3) / 4, 256, 0, stream>>>(emb, tab, V);
        dim3 grid(B, 2);
        knrm_main5<<<grid, 256, 0, stream>>>(q1, d1, q2, d2, tab,
                                             W0, b0, W1, b1, W2, b2, lg, B);
        knrm_final<<<(B + 255) / 256, 256, 0, stream>>>(lg, out, B);
    } else {
        knrm_mono<<<B, 256, 0, stream>>>(q1, d1, q2, d2, emb,
                                         W0, b0, W1, b1, W2, b2, out);
    }
}